// Round 4
// baseline (148.609 us; speedup 1.0000x reference)
//
#include <hip/hip_runtime.h>
#include <stdint.h>

#define XC 4096      // CB*BS
#define MT 128       // batch rows per workgroup (main path)
#define FB_MT 256    // fallback tile
#define NNZ 13       // nnz blocks per row block (setup guarantees)

typedef __attribute__((ext_vector_type(8))) short short8;
typedef __attribute__((ext_vector_type(4))) float f32x4;

static __device__ __forceinline__ unsigned short f2bf(float f) {
    union { float f; unsigned int u; } c; c.f = f;
    unsigned int u = c.u;
    unsigned int r = 0x7FFFu + ((u >> 16) & 1u);
    return (unsigned short)((u + r) >> 16);
}
static __device__ __forceinline__ unsigned int pk2(float a, float b) {   // round-nearest
    return (unsigned int)f2bf(a) | ((unsigned int)f2bf(b) << 16);
}
// one-instruction bf16x2 pack by truncation (verified round 3)
static __device__ __forceinline__ unsigned int pktr(float e, float o) {
    return __builtin_amdgcn_perm(__float_as_uint(o), __float_as_uint(e), 0x07060302u);
}

// ---- prep: w*mask -> bf16 (RN), written in MFMA B-fragment order ----
// dest short idx = n*1024 + (o>>4)*512 + (s>>3)*128 + (o&15)*8 + (s&7)
__global__ void prep_w(const float* __restrict__ w, const float* __restrict__ m,
                       unsigned short* __restrict__ out, int nf4) {
    int i = blockIdx.x * 256 + threadIdx.x;
    if (i >= nf4) return;
    float4 a = ((const float4*)w)[i];
    float4 b = ((const float4*)m)[i];
    unsigned int lo = pk2(a.x * b.x, a.y * b.y);
    unsigned int hi = pk2(a.z * b.z, a.w * b.w);
    int e = i * 4;
    int n = e >> 10, rem = e & 1023;
    int o = rem >> 5, s = rem & 31;
    int dest = n * 1024 + ((o >> 4) << 9) + ((s >> 3) << 7) + ((o & 15) << 3) + (s & 7);
    *(uint2*)(out + dest) = make_uint2(lo, hi);
}

// ---- main: zero-LDS, zero-barrier register pipeline, prefetch distance 2 ----
// grid = 16 mt * 128 r (bx&127=r: consecutive blocks share mt x-slice; 2MB/XCD fits L2).
// Wave owns 32 batch rows (2 mi tiles). A: fp32 saddr-gather -> v_perm trunc bf16.
// B: streamed coalesced dwordx4 from fragment-ordered wbf (L2-resident, 3.4MB).
__global__ __launch_bounds__(256, 2) void bsl_reg2(
    const float* __restrict__ x, const int* __restrict__ cols,
    const unsigned short* __restrict__ wbf, const float* __restrict__ bias,
    float* __restrict__ out)
{
    const int bx   = blockIdx.x;
    const int r    = bx & 127;
    const int mt   = bx >> 7;
    const int row0 = mt * MT;

    const int lane = threadIdx.x & 63;
    const int wv   = threadIdx.x >> 6;
    const int l15  = lane & 15;
    const int quad = lane >> 4;

    // wave-uniform col sequence in SGPRs -> saddr-form loads, no per-iter VALU
    int cseq[NNZ];
    #pragma unroll
    for (int nn = 0; nn < NNZ; ++nn)
        cseq[nn] = __builtin_amdgcn_readfirstlane(cols[r * NNZ + nn]);

    // per-lane x float offsets for the 2 mi tiles (quad*8 floats within 32-col chunk)
    const int row0w = row0 + wv * 32;
    int voff[2];
    #pragma unroll
    for (int mi = 0; mi < 2; ++mi)
        voff[mi] = (row0w + mi * 16 + l15) * XC + quad * 8;

    // B-frag pointer: lane reads 16B at (r, nn, half, quad, l15) in frag order
    const unsigned short* wbp = wbf + (size_t)r * (NNZ * 1024) + (quad << 7) + (l15 << 3);

    f32x4 acc[2][2];
    #pragma unroll
    for (int i = 0; i < 2; ++i)
        #pragma unroll
        for (int j = 0; j < 2; ++j)
            acc[i][j] = (f32x4){0.f, 0.f, 0.f, 0.f};

    // pipeline buffers: x 3-deep (in-use / in-flight / just-issued), w 2-deep
    float4 xb[3][2][2];      // [slot][mi][half]
    short8 wB[2][2];         // [slot][half]

    #pragma unroll
    for (int p = 0; p < 2; ++p) {
        const float* xc = x + (size_t)cseq[p] * 32;
        #pragma unroll
        for (int mi = 0; mi < 2; ++mi) {
            xb[p][mi][0] = *(const float4*)(xc + voff[mi]);
            xb[p][mi][1] = *(const float4*)(xc + voff[mi] + 4);
        }
        wB[p][0] = *(const short8*)(wbp + p * 1024);
        wB[p][1] = *(const short8*)(wbp + p * 1024 + 512);
    }

    #pragma unroll
    for (int nn = 0; nn < NNZ; ++nn) {
        const int xs = nn % 3;
        const int ws = nn & 1;

        // convert current chunk (compiler waits only on slot xs's 4 loads)
        union { short8 s; unsigned int u[4]; } afr[2];
        #pragma unroll
        for (int mi = 0; mi < 2; ++mi) {
            const float4 lo = xb[xs][mi][0], hi = xb[xs][mi][1];
            afr[mi].u[0] = pktr(lo.x, lo.y);
            afr[mi].u[1] = pktr(lo.z, lo.w);
            afr[mi].u[2] = pktr(hi.x, hi.y);
            afr[mi].u[3] = pktr(hi.z, hi.w);
        }

        // prefetch chunk nn+2 x into the freed slot (distance-2 lookahead)
        if (nn + 2 < NNZ) {
            const float* xc = x + (size_t)cseq[nn + 2] * 32;
            #pragma unroll
            for (int mi = 0; mi < 2; ++mi) {
                xb[(nn + 2) % 3][mi][0] = *(const float4*)(xc + voff[mi]);
                xb[(nn + 2) % 3][mi][1] = *(const float4*)(xc + voff[mi] + 4);
            }
        }

        acc[0][0] = __builtin_amdgcn_mfma_f32_16x16x32_bf16(afr[0].s, wB[ws][0], acc[0][0], 0, 0, 0);
        acc[0][1] = __builtin_amdgcn_mfma_f32_16x16x32_bf16(afr[0].s, wB[ws][1], acc[0][1], 0, 0, 0);
        acc[1][0] = __builtin_amdgcn_mfma_f32_16x16x32_bf16(afr[1].s, wB[ws][0], acc[1][0], 0, 0, 0);
        acc[1][1] = __builtin_amdgcn_mfma_f32_16x16x32_bf16(afr[1].s, wB[ws][1], acc[1][1], 0, 0, 0);

        // stream w for chunk nn+2 into the slot just consumed
        if (nn + 2 < NNZ) {
            wB[ws][0] = *(const short8*)(wbp + (nn + 2) * 1024);
            wB[ws][1] = *(const short8*)(wbp + (nn + 2) * 1024 + 512);
        }
    }

    // epilogue: C/D layout col=l15(=o), row=quad*4+reg(=m)
    const float b0v = bias[r * 32 + l15];
    const float b1v = bias[r * 32 + 16 + l15];
    #pragma unroll
    for (int mi = 0; mi < 2; ++mi) {
        const int rbase = row0 + wv * 32 + mi * 16 + quad * 4;
        #pragma unroll
        for (int reg = 0; reg < 4; ++reg) {
            float* op = out + (size_t)(rbase + reg) * XC + r * 32;
            op[l15]      = acc[mi][0][reg] + b0v;
            op[16 + l15] = acc[mi][1][reg] + b1v;
        }
    }
}

// ---- fallback (unexpected shape / tiny ws): barriered LDS version ----
__global__ __launch_bounds__(256, 3) void bsl_fallback(
    const float* __restrict__ x, const int* __restrict__ crow,
    const int* __restrict__ cols, const float* __restrict__ wf,
    const float* __restrict__ mf, const float* __restrict__ bias,
    float* __restrict__ out)
{
    __shared__ unsigned short w_lds[NNZ][32][40];
    __shared__ unsigned short x_lds[FB_MT][40];

    const int tid = threadIdx.x;
    const int bx  = blockIdx.x;
    const int r   = bx & 127;
    const int mt  = bx >> 7;
    const int row0 = mt * FB_MT;
    const int start = crow[r];
    const int nnzr  = crow[r + 1] - start;

    const float4* wsrc = (const float4*)(wf + (size_t)start * 1024);
    const float4* msrc = (const float4*)(mf + (size_t)start * 1024);
    for (int i = tid; i < nnzr * 256; i += 256) {
        int nn = i >> 8, rem = i & 255;
        int o = rem >> 3, sg = rem & 7;
        float4 a = wsrc[i], b = msrc[i];
        *(uint2*)&w_lds[nn][o][sg * 4] =
            make_uint2(pk2(a.x * b.x, a.y * b.y), pk2(a.z * b.z, a.w * b.w));
    }

    const int lane = tid & 63;
    const int wv   = tid >> 6;
    const int l15  = lane & 15;
    const int quad = lane >> 4;

    f32x4 acc[4][2];
    #pragma unroll
    for (int i = 0; i < 4; ++i)
        #pragma unroll
        for (int j = 0; j < 2; ++j)
            acc[i][j] = (f32x4){0.f, 0.f, 0.f, 0.f};

    const int s4 = tid & 7;
    const int rr = tid >> 3;
    float4 v[8];
    {
        int c = cols[start];
        const float* xb = x + (size_t)(row0 + rr) * XC + c * 32 + s4 * 4;
        #pragma unroll
        for (int j = 0; j < 8; ++j) v[j] = *(const float4*)(xb + (size_t)j * 32 * XC);
    }

    for (int nn = 0; nn < nnzr; ++nn) {
        __syncthreads();
        #pragma unroll
        for (int j = 0; j < 8; ++j)
            *(uint2*)&x_lds[rr + j * 32][s4 * 4] =
                make_uint2(pk2(v[j].x, v[j].y), pk2(v[j].z, v[j].w));
        __syncthreads();

        if (nn + 1 < nnzr) {
            int c = cols[start + nn + 1];
            const float* xb = x + (size_t)(row0 + rr) * XC + c * 32 + s4 * 4;
            #pragma unroll
            for (int j = 0; j < 8; ++j) v[j] = *(const float4*)(xb + (size_t)j * 32 * XC);
        }

        short8 b0 = *(const short8*)&w_lds[nn][l15][quad * 8];
        short8 b1 = *(const short8*)&w_lds[nn][16 + l15][quad * 8];
        #pragma unroll
        for (int mi = 0; mi < 4; ++mi) {
            short8 a = *(const short8*)&x_lds[wv * 64 + mi * 16 + l15][quad * 8];
            acc[mi][0] = __builtin_amdgcn_mfma_f32_16x16x32_bf16(a, b0, acc[mi][0], 0, 0, 0);
            acc[mi][1] = __builtin_amdgcn_mfma_f32_16x16x32_bf16(a, b1, acc[mi][1], 0, 0, 0);
        }
    }

    const float b0v = bias[r * 32 + l15];
    const float b1v = bias[r * 32 + 16 + l15];
    #pragma unroll
    for (int mi = 0; mi < 4; ++mi) {
        const int rbase = row0 + wv * 64 + mi * 16 + quad * 4;
        #pragma unroll
        for (int reg = 0; reg < 4; ++reg) {
            float* op = out + (size_t)(rbase + reg) * XC + r * 32;
            op[l15]      = acc[mi][0][reg] + b0v;
            op[16 + l15] = acc[mi][1][reg] + b1v;
        }
    }
}

extern "C" void kernel_launch(void* const* d_in, const int* in_sizes, int n_in,
                              void* d_out, int out_size, void* d_ws, size_t ws_size,
                              hipStream_t stream) {
    const float* x      = (const float*)d_in[0];
    const int*   crow   = (const int*)d_in[1];
    const int*   cols   = (const int*)d_in[2];
    const float* mask   = (const float*)d_in[3];
    const float* weight = (const float*)d_in[4];
    const float* bias   = (const float*)d_in[5];
    float* out = (float*)d_out;

    const int xel   = in_sizes[0];        // 2048*4096
    const int wel   = in_sizes[4];        // 1664*1024
    const int rb    = in_sizes[1] - 1;    // 128
    const int batch = xel / XC;           // 2048

    const size_t wb_bytes = (size_t)wel * 2;
    const bool fast = (ws_size >= wb_bytes) && (rb == 128) &&
                      (in_sizes[2] == rb * NNZ) && (batch % MT == 0);

    if (fast) {
        unsigned short* wbf = (unsigned short*)d_ws;
        int nw4 = wel / 4;
        prep_w<<<dim3((nw4 + 255) / 256), dim3(256), 0, stream>>>(weight, mask, wbf, nw4);
        bsl_reg2<<<dim3(rb * (batch / MT)), dim3(256), 0, stream>>>(x, cols, wbf, bias, out);
    } else {
        bsl_fallback<<<dim3(rb * (batch / FB_MT)), dim3(256), 0, stream>>>(
            x, crow, cols, weight, mask, bias, out);
    }
}

// Round 5
// 128.907 us; speedup vs baseline: 1.1528x; 1.1528x over previous
//
#include <hip/hip_runtime.h>
#include <stdint.h>

#define XC 4096      // CB*BS
#define MT 128       // batch rows per workgroup (main path)
#define FB_MT 256    // fallback tile
#define NNZ 13       // nnz blocks per row block (setup guarantees)

typedef __attribute__((ext_vector_type(8))) short short8;
typedef __attribute__((ext_vector_type(4))) float f32x4;

static __device__ __forceinline__ unsigned short f2bf(float f) {
    union { float f; unsigned int u; } c; c.f = f;
    unsigned int u = c.u;
    unsigned int r = 0x7FFFu + ((u >> 16) & 1u);
    return (unsigned short)((u + r) >> 16);
}
static __device__ __forceinline__ unsigned int pk2(float a, float b) {   // round-nearest
    return (unsigned int)f2bf(a) | ((unsigned int)f2bf(b) << 16);
}
// one-instruction bf16x2 pack by truncation (correctness verified rounds 3-4)
static __device__ __forceinline__ unsigned int pktr(float e, float o) {
    return __builtin_amdgcn_perm(__float_as_uint(o), __float_as_uint(e), 0x07060302u);
}

// async global->LDS DMA, 16B/lane; LDS dest = wave-uniform base + lane*16
#define GLD_LDS16(g, l) __builtin_amdgcn_global_load_lds(                      \
    (const __attribute__((address_space(1))) void*)(g),                        \
    (__attribute__((address_space(3))) void*)(l), 16, 0, 0)

// ---- prep: w*mask -> bf16 (RN), written in MFMA B-fragment order ----
// dest short idx = n*1024 + (o>>4)*512 + (s>>3)*128 + (o&15)*8 + (s&7)
__global__ void prep_w(const float* __restrict__ w, const float* __restrict__ m,
                       unsigned short* __restrict__ out, int nf4) {
    int i = blockIdx.x * 256 + threadIdx.x;
    if (i >= nf4) return;
    float4 a = ((const float4*)w)[i];
    float4 b = ((const float4*)m)[i];
    unsigned int lo = pk2(a.x * b.x, a.y * b.y);
    unsigned int hi = pk2(a.z * b.z, a.w * b.w);
    int e = i * 4;
    int n = e >> 10, rem = e & 1023;
    int o = rem >> 5, s = rem & 31;
    int dest = n * 1024 + ((o >> 4) << 9) + ((s >> 3) << 7) + ((o & 15) << 3) + (s & 7);
    *(uint2*)(out + dest) = make_uint2(lo, hi);
}

// ---- main: fp32 x staged by global_load_lds DMA (in-flight data holds ZERO
// VGPRs -> allocator cannot serialize the pipeline), 3-deep wave-private bufs,
// explicit vmcnt discipline; w preloaded to VGPRs; XCD-aware block swizzle.
__global__ __launch_bounds__(256, 3) void bsl_dma(
    const float* __restrict__ x, const int* __restrict__ cols,
    const unsigned short* __restrict__ wbf, const float* __restrict__ bias,
    float* __restrict__ out)
{
    // 4 waves * 3 slots * 4 KB (32 rows x 32 fp32), XOR-swizzled
    __shared__ __align__(16) unsigned char x_lds[4 * 3 * 4096];

    const int bx = blockIdx.x;
    // XCD k (= bx&7) handles mt in {2k, 2k+1}: per-XCD x slice = 2MB -> L2-resident
    const int r  = (bx >> 3) & 127;
    const int mt = ((bx & 7) << 1) | (bx >> 10);
    const int row0 = mt * MT;

    const int lane = threadIdx.x & 63;
    const int wv   = threadIdx.x >> 6;
    const int l15  = lane & 15;
    const int quad = lane >> 4;

    // wave-uniform col sequence -> SGPRs
    int cseq[NNZ];
    #pragma unroll
    for (int nn = 0; nn < NNZ; ++nn)
        cseq[nn] = __builtin_amdgcn_readfirstlane(cols[r * NNZ + nn]);

    // preload ALL w frags (26 dwordx4, ~104 VGPR). In-loop vm ops are then
    // exclusively the x GLDs -> exact vmcnt accounting below.
    short8 wfrag[NNZ][2];
    {
        const unsigned short* wbp = wbf + (size_t)r * (NNZ * 1024) + (quad << 7) + (l15 << 3);
        #pragma unroll
        for (int nn = 0; nn < NNZ; ++nn) {
            wfrag[nn][0] = *(const short8*)(wbp + nn * 1024);
            wfrag[nn][1] = *(const short8*)(wbp + nn * 1024 + 512);
        }
    }

    // staging geometry: GLD instr j covers rows j*8..j*8+7; lane -> row j*8+(lane>>3),
    // slot lane&7; global seg s = slot ^ (row&7)  (XOR swizzle for conflict-free reads)
    const int row0w = row0 + wv * 32;
    const int seg   = (lane & 7) ^ ((lane >> 3) & 7);
    const float* xlane = x + ((size_t)row0w + (lane >> 3)) * XC + seg * 4;
    unsigned char* lb = &x_lds[wv * 12288];

    #pragma unroll
    for (int p = 0; p < 3; ++p) {           // pre-issue chunks 0..2
        const float* g = xlane + (size_t)cseq[p] * 32;
        unsigned char* l = lb + p * 4096;
        #pragma unroll
        for (int j = 0; j < 4; ++j)
            GLD_LDS16(g + (size_t)j * 8 * XC, l + j * 1024);
    }

    f32x4 acc[2][2];
    #pragma unroll
    for (int i = 0; i < 2; ++i)
        #pragma unroll
        for (int j = 0; j < 2; ++j)
            acc[i][j] = (f32x4){0.f, 0.f, 0.f, 0.f};

    const int rp = l15 & 7;
    const int slotA = ((quad * 2) ^ rp) * 16;        // byte offsets within row
    const int slotB = ((quad * 2 + 1) ^ rp) * 16;

    #pragma unroll
    for (int nn = 0; nn < NNZ; ++nn) {
        // chunk nn resident when only chunks nn+1, nn+2 remain outstanding
        if (nn < NNZ - 2)       asm volatile("s_waitcnt vmcnt(8)" ::: "memory");
        else if (nn == NNZ - 2) asm volatile("s_waitcnt vmcnt(4)" ::: "memory");
        else                    asm volatile("s_waitcnt vmcnt(0)" ::: "memory");

        const unsigned char* cb = lb + (nn % 3) * 4096;
        union { short8 s; unsigned int u[4]; } afr[2];
        #pragma unroll
        for (int mi = 0; mi < 2; ++mi) {
            const int ro = (mi * 16 + l15) * 128;
            float4 alo = *(const float4*)(cb + ro + slotA);   // floats quad*8..+3
            float4 ahi = *(const float4*)(cb + ro + slotB);   // floats quad*8+4..+7
            afr[mi].u[0] = pktr(alo.x, alo.y);
            afr[mi].u[1] = pktr(alo.z, alo.w);
            afr[mi].u[2] = pktr(ahi.x, ahi.y);
            afr[mi].u[3] = pktr(ahi.z, ahi.w);
        }

        acc[0][0] = __builtin_amdgcn_mfma_f32_16x16x32_bf16(afr[0].s, wfrag[nn][0], acc[0][0], 0, 0, 0);
        acc[0][1] = __builtin_amdgcn_mfma_f32_16x16x32_bf16(afr[0].s, wfrag[nn][1], acc[0][1], 0, 0, 0);
        acc[1][0] = __builtin_amdgcn_mfma_f32_16x16x32_bf16(afr[1].s, wfrag[nn][0], acc[1][0], 0, 0, 0);
        acc[1][1] = __builtin_amdgcn_mfma_f32_16x16x32_bf16(afr[1].s, wfrag[nn][1], acc[1][1], 0, 0, 0);

        // reuse slot nn%3 for chunk nn+3: safe, the MFMAs' lgkm waits above
        // guarantee this slot's ds_reads already returned (in-order LDS)
        if (nn + 3 < NNZ) {
            const float* g = xlane + (size_t)cseq[nn + 3] * 32;
            unsigned char* l = lb + ((nn + 3) % 3) * 4096;
            #pragma unroll
            for (int j = 0; j < 4; ++j)
                GLD_LDS16(g + (size_t)j * 8 * XC, l + j * 1024);
        }
    }

    // epilogue: C/D layout col=l15(=o), row=quad*4+reg(=m)
    const float b0v = bias[r * 32 + l15];
    const float b1v = bias[r * 32 + 16 + l15];
    #pragma unroll
    for (int mi = 0; mi < 2; ++mi) {
        const int rbase = row0w + mi * 16 + quad * 4;
        #pragma unroll
        for (int reg = 0; reg < 4; ++reg) {
            float* op = out + (size_t)(rbase + reg) * XC + r * 32;
            op[l15]      = acc[mi][0][reg] + b0v;
            op[16 + l15] = acc[mi][1][reg] + b1v;
        }
    }
}

// ---- fallback (unexpected shape / tiny ws): barriered LDS version ----
__global__ __launch_bounds__(256, 3) void bsl_fallback(
    const float* __restrict__ x, const int* __restrict__ crow,
    const int* __restrict__ cols, const float* __restrict__ wf,
    const float* __restrict__ mf, const float* __restrict__ bias,
    float* __restrict__ out)
{
    __shared__ unsigned short w_lds[NNZ][32][40];
    __shared__ unsigned short x_lds[FB_MT][40];

    const int tid = threadIdx.x;
    const int bx  = blockIdx.x;
    const int r   = bx & 127;
    const int mt  = bx >> 7;
    const int row0 = mt * FB_MT;
    const int start = crow[r];
    const int nnzr  = crow[r + 1] - start;

    const float4* wsrc = (const float4*)(wf + (size_t)start * 1024);
    const float4* msrc = (const float4*)(mf + (size_t)start * 1024);
    for (int i = tid; i < nnzr * 256; i += 256) {
        int nn = i >> 8, rem = i & 255;
        int o = rem >> 3, sg = rem & 7;
        float4 a = wsrc[i], b = msrc[i];
        *(uint2*)&w_lds[nn][o][sg * 4] =
            make_uint2(pk2(a.x * b.x, a.y * b.y), pk2(a.z * b.z, a.w * b.w));
    }

    const int lane = tid & 63;
    const int wv   = tid >> 6;
    const int l15  = lane & 15;
    const int quad = lane >> 4;

    f32x4 acc[4][2];
    #pragma unroll
    for (int i = 0; i < 4; ++i)
        #pragma unroll
        for (int j = 0; j < 2; ++j)
            acc[i][j] = (f32x4){0.f, 0.f, 0.f, 0.f};

    const int s4 = tid & 7;
    const int rr = tid >> 3;
    float4 v[8];
    {
        int c = cols[start];
        const float* xb = x + (size_t)(row0 + rr) * XC + c * 32 + s4 * 4;
        #pragma unroll
        for (int j = 0; j < 8; ++j) v[j] = *(const float4*)(xb + (size_t)j * 32 * XC);
    }

    for (int nn = 0; nn < nnzr; ++nn) {
        __syncthreads();
        #pragma unroll
        for (int j = 0; j < 8; ++j)
            *(uint2*)&x_lds[rr + j * 32][s4 * 4] =
                make_uint2(pk2(v[j].x, v[j].y), pk2(v[j].z, v[j].w));
        __syncthreads();

        if (nn + 1 < nnzr) {
            int c = cols[start + nn + 1];
            const float* xb = x + (size_t)(row0 + rr) * XC + c * 32 + s4 * 4;
            #pragma unroll
            for (int j = 0; j < 8; ++j) v[j] = *(const float4*)(xb + (size_t)j * 32 * XC);
        }

        short8 b0 = *(const short8*)&w_lds[nn][l15][quad * 8];
        short8 b1 = *(const short8*)&w_lds[nn][16 + l15][quad * 8];
        #pragma unroll
        for (int mi = 0; mi < 4; ++mi) {
            short8 a = *(const short8*)&x_lds[wv * 64 + mi * 16 + l15][quad * 8];
            acc[mi][0] = __builtin_amdgcn_mfma_f32_16x16x32_bf16(a, b0, acc[mi][0], 0, 0, 0);
            acc[mi][1] = __builtin_amdgcn_mfma_f32_16x16x32_bf16(a, b1, acc[mi][1], 0, 0, 0);
        }
    }

    const float b0v = bias[r * 32 + l15];
    const float b1v = bias[r * 32 + 16 + l15];
    #pragma unroll
    for (int mi = 0; mi < 4; ++mi) {
        const int rbase = row0 + wv * 64 + mi * 16 + quad * 4;
        #pragma unroll
        for (int reg = 0; reg < 4; ++reg) {
            float* op = out + (size_t)(rbase + reg) * XC + r * 32;
            op[l15]      = acc[mi][0][reg] + b0v;
            op[16 + l15] = acc[mi][1][reg] + b1v;
        }
    }
}

extern "C" void kernel_launch(void* const* d_in, const int* in_sizes, int n_in,
                              void* d_out, int out_size, void* d_ws, size_t ws_size,
                              hipStream_t stream) {
    const float* x      = (const float*)d_in[0];
    const int*   crow   = (const int*)d_in[1];
    const int*   cols   = (const int*)d_in[2];
    const float* mask   = (const float*)d_in[3];
    const float* weight = (const float*)d_in[4];
    const float* bias   = (const float*)d_in[5];
    float* out = (float*)d_out;

    const int xel   = in_sizes[0];        // 2048*4096
    const int wel   = in_sizes[4];        // 1664*1024
    const int rb    = in_sizes[1] - 1;    // 128
    const int batch = xel / XC;           // 2048

    const size_t wb_bytes = (size_t)wel * 2;
    const bool fast = (ws_size >= wb_bytes) && (rb == 128) &&
                      (in_sizes[2] == rb * NNZ) && (batch == 2048);

    if (fast) {
        unsigned short* wbf = (unsigned short*)d_ws;
        int nw4 = wel / 4;
        prep_w<<<dim3((nw4 + 255) / 256), dim3(256), 0, stream>>>(weight, mask, wbf, nw4);
        bsl_dma<<<dim3(rb * (batch / MT)), dim3(256), 0, stream>>>(x, cols, wbf, bias, out);
    } else {
        bsl_fallback<<<dim3(rb * (batch / FB_MT)), dim3(256), 0, stream>>>(
            x, crow, cols, weight, mask, bias, out);
    }
}